// Round 1
// baseline (280.818 us; speedup 1.0000x reference)
//
#include <hip/hip_runtime.h>

typedef __bf16 bx8 __attribute__((ext_vector_type(8)));
typedef __bf16 bx4 __attribute__((ext_vector_type(4)));
typedef float  fx4 __attribute__((ext_vector_type(4)));

#define B_   4
#define S_   2048
#define DIN  1024
#define DH   1024

#define MB ((size_t)1 << 20)
// workspace layout (bytes)
#define WS_A1 ((size_t)0)          // seq1 bf16, 16MB   (aliased by Pu later)
#define WS_A2 ((size_t)16*MB)      // seq2 bf16, 16MB   (aliased by Pu later)
#define WS_PU ((size_t)0)          // exp-scores bf16, 32MB (after QKV done)
#define WS_WQ ((size_t)32*MB)
#define WS_WK ((size_t)34*MB)
#define WS_WV ((size_t)36*MB)
#define WS_Q  ((size_t)38*MB)      // q bf16 [B*S, DH] 16MB
#define WS_K  ((size_t)54*MB)      // k bf16 [B*S, DH] 16MB
#define WS_VT ((size_t)70*MB)      // v^T bf16 [B, DH, S] 16MB
#define WS_CS ((size_t)86*MB)      // colsum fp32 [B, S] 32KB

// ---------------------------------------------------------------- cvt f32->bf16
__global__ void cvt_f32_bf16(const float* __restrict__ in, __bf16* __restrict__ out) {
  size_t i = (size_t)blockIdx.x * blockDim.x + threadIdx.x;
  fx4 lo = ((const fx4*)in)[2 * i];
  fx4 hi = ((const fx4*)in)[2 * i + 1];
  bx8 o;
#pragma unroll
  for (int j = 0; j < 4; j++) { o[j] = (__bf16)lo[j]; o[j + 4] = (__bf16)hi[j]; }
  ((bx8*)out)[i] = o;
}

// ---------------------------------------------------------------- GEMM C = A @ B^T
// A: [M,K] bf16 row-major (lda=K), Bm: [N,K] bf16 row-major (ldb=K)
// 128x128 tile, BK=32, 4 waves (2x2), each wave 64x64 = 4x4 frags of 16x16x32.
#define GLD16(g, l)                                                              \
  __builtin_amdgcn_global_load_lds(                                              \
      (const __attribute__((address_space(1))) void*)(const void*)(g),           \
      (__attribute__((address_space(3))) void*)(void*)(l), 16, 0, 0)

enum { EP_BF16 = 0, EP_VT = 1, EP_EXP = 2, EP_F32 = 3 };

template <int EPI>
__global__ __launch_bounds__(256) void gemm_bt(
    const __bf16* __restrict__ A, const __bf16* __restrict__ Bm,
    void* __restrict__ Cout, const int* __restrict__ Mask,
    int M, int N, int K, long sA, long sB) {
  const int bz = blockIdx.z;
  A  += (long)bz * sA;
  Bm += (long)bz * sB;
  const int brow = blockIdx.y * 128;
  const int bcol = blockIdx.x * 128;

  __shared__ __align__(16) __bf16 As[128 * 32];
  __shared__ __align__(16) __bf16 Bs[128 * 32];

  const int tid  = threadIdx.x;
  const int wid  = tid >> 6;
  const int lane = tid & 63;
  const int wr = wid >> 1, wc = wid & 1;

  fx4 acc[4][4] = {};

  // staging: per wave 2 chunks of 1024B each for A and B tiles (linear LDS)
  const int ldrow = wid * 32 + (lane >> 2);  // chunk c=0 row; c=1 adds 16
  const int lcol  = (lane & 3) * 8;
  const __bf16* gA = A + (size_t)(brow + ldrow) * K + lcol;
  const __bf16* gB = Bm + (size_t)(bcol + ldrow) * K + lcol;
  char* lA = (char*)As + wid * 2048;
  char* lB = (char*)Bs + wid * 2048;

  const int ar = wr * 64 + (lane & 15);  // A-frag row in tile (+m*16)
  const int br = wc * 64 + (lane & 15);  // B-frag row in tile (+n*16)
  const int kf = (lane >> 4) * 8;        // k offset within BK=32

  for (int k0 = 0; k0 < K; k0 += 32) {
    __syncthreads();
    GLD16(gA + k0,           lA);
    GLD16(gA + k0 + 16 * K,  lA + 1024);
    GLD16(gB + k0,           lB);
    GLD16(gB + k0 + 16 * K,  lB + 1024);
    __syncthreads();
    bx8 av[4], bv[4];
#pragma unroll
    for (int m = 0; m < 4; m++) av[m] = *(const bx8*)&As[(ar + m * 16) * 32 + kf];
#pragma unroll
    for (int n = 0; n < 4; n++) bv[n] = *(const bx8*)&Bs[(br + n * 16) * 32 + kf];
#pragma unroll
    for (int m = 0; m < 4; m++)
#pragma unroll
      for (int n = 0; n < 4; n++)
        acc[m][n] = __builtin_amdgcn_mfma_f32_16x16x32_bf16(av[m], bv[n], acc[m][n], 0, 0, 0);
  }

  // epilogue: C/D layout col = lane&15, row = (lane>>4)*4 + j   [verified m89]
  const int r0 = wr * 64 + (lane >> 4) * 4;
  const int c0 = wc * 64 + (lane & 15);

  if (EPI == EP_BF16) {
    __bf16* C = (__bf16*)Cout;
#pragma unroll
    for (int m = 0; m < 4; m++) {
      int row = brow + r0 + m * 16;
#pragma unroll
      for (int n = 0; n < 4; n++) {
        int col = bcol + c0 + n * 16;
#pragma unroll
        for (int j = 0; j < 4; j++)
          C[(size_t)(row + j) * N + col] = (__bf16)acc[m][n][j];
      }
    }
  } else if (EPI == EP_VT) {
    // write C^T into vT[b][col][s], b = row/2048, s = row%2048 (4 consecutive s)
    __bf16* C = (__bf16*)Cout;
#pragma unroll
    for (int m = 0; m < 4; m++) {
      int row  = brow + r0 + m * 16;
      size_t bb = (size_t)(row >> 11) << 21;  // batch * DH*S
      int sidx = row & 2047;
#pragma unroll
      for (int n = 0; n < 4; n++) {
        int col = bcol + c0 + n * 16;
        bx4 t;
#pragma unroll
        for (int j = 0; j < 4; j++) t[j] = (__bf16)acc[m][n][j];
        *(bx4*)&C[bb + (size_t)col * S_ + sidx] = t;
      }
    }
  } else if (EPI == EP_EXP) {
    __bf16* C    = (__bf16*)Cout + (size_t)bz * ((size_t)S_ * S_);
    const int* Mk = Mask + (size_t)bz * ((size_t)S_ * S_);
#pragma unroll
    for (int m = 0; m < 4; m++) {
      int row = brow + r0 + m * 16;
#pragma unroll
      for (int n = 0; n < 4; n++) {
        int col = bcol + c0 + n * 16;
#pragma unroll
        for (int j = 0; j < 4; j++) {
          float s = acc[m][n][j] * 0.03125f;  // 1/sqrt(1024)
          float p = Mk[(size_t)(row + j) * N + col] ? 1.0f : __expf(s);
          C[(size_t)(row + j) * N + col] = (__bf16)p;
        }
      }
    }
  } else {  // EP_F32
    float* C = (float*)Cout + (size_t)bz * ((size_t)S_ * DH);
#pragma unroll
    for (int m = 0; m < 4; m++) {
      int row = brow + r0 + m * 16;
#pragma unroll
      for (int n = 0; n < 4; n++) {
        int col = bcol + c0 + n * 16;
#pragma unroll
        for (int j = 0; j < 4; j++)
          C[(size_t)(row + j) * N + col] = acc[m][n][j];
      }
    }
  }
}

// ---------------------------------------------------------------- column sums of Pu
__global__ void colsum_partial(const __bf16* __restrict__ Pu, float* __restrict__ cs) {
  int b  = blockIdx.z;
  int k  = blockIdx.x * 256 + threadIdx.x;
  int q0 = blockIdx.y * 256;
  const __bf16* P = Pu + (size_t)b * S_ * S_ + (size_t)q0 * S_ + k;
  float s = 0.f;
#pragma unroll 8
  for (int q = 0; q < 256; q++) s += (float)P[(size_t)q * S_];
  atomicAdd(&cs[b * S_ + k], s);
}

// ---------------------------------------------------------------- vT[b][h][k] /= colsum[b][k]
__global__ void scale_vt(__bf16* __restrict__ vT, const float* __restrict__ cs) {
  size_t i = (size_t)blockIdx.x * blockDim.x + threadIdx.x;
  size_t e = i * 8;
  int b = (int)(e >> 21);      // DH*S = 2^21 elems per batch
  int k = (int)(e & (S_ - 1)); // contiguous along k
  bx8 v = ((bx8*)vT)[i];
  const float* c = cs + (size_t)b * S_ + k;
#pragma unroll
  for (int j = 0; j < 8; j++) v[j] = (__bf16)((float)v[j] / c[j]);
  ((bx8*)vT)[i] = v;
}

// ---------------------------------------------------------------- launch
extern "C" void kernel_launch(void* const* d_in, const int* in_sizes, int n_in,
                              void* d_out, int out_size, void* d_ws, size_t ws_size,
                              hipStream_t stream) {
  const float* seq1 = (const float*)d_in[0];
  const float* seq2 = (const float*)d_in[1];
  const int*   mask = (const int*)d_in[2];
  const float* Wq   = (const float*)d_in[3];
  const float* Wk   = (const float*)d_in[4];
  const float* Wv   = (const float*)d_in[5];

  char* ws = (char*)d_ws;
  __bf16* A1  = (__bf16*)(ws + WS_A1);
  __bf16* A2  = (__bf16*)(ws + WS_A2);
  __bf16* Pu  = (__bf16*)(ws + WS_PU);
  __bf16* WQb = (__bf16*)(ws + WS_WQ);
  __bf16* WKb = (__bf16*)(ws + WS_WK);
  __bf16* WVb = (__bf16*)(ws + WS_WV);
  __bf16* qb  = (__bf16*)(ws + WS_Q);
  __bf16* kb  = (__bf16*)(ws + WS_K);
  __bf16* vTb = (__bf16*)(ws + WS_VT);
  float*  cs  = (float*)(ws + WS_CS);

  // fp32 -> bf16 conversions
  cvt_f32_bf16<<<4096, 256, 0, stream>>>(seq1, A1);  // 8192*1024/8/256
  cvt_f32_bf16<<<4096, 256, 0, stream>>>(seq2, A2);
  cvt_f32_bf16<<<512, 256, 0, stream>>>(Wq, WQb);    // 1024*1024/8/256
  cvt_f32_bf16<<<512, 256, 0, stream>>>(Wk, WKb);
  cvt_f32_bf16<<<512, 256, 0, stream>>>(Wv, WVb);

  // projections: q = seq1 @ Wq^T ; k = seq2 @ Wk^T ; vT = (seq2 @ Wv^T)^T
  gemm_bt<EP_BF16><<<dim3(DH / 128, (B_ * S_) / 128, 1), 256, 0, stream>>>(
      A1, WQb, qb, nullptr, B_ * S_, DH, DIN, 0, 0);
  gemm_bt<EP_BF16><<<dim3(DH / 128, (B_ * S_) / 128, 1), 256, 0, stream>>>(
      A2, WKb, kb, nullptr, B_ * S_, DH, DIN, 0, 0);
  gemm_bt<EP_VT><<<dim3(DH / 128, (B_ * S_) / 128, 1), 256, 0, stream>>>(
      A2, WVb, vTb, nullptr, B_ * S_, DH, DIN, 0, 0);

  // Pu[b,q,k] = mask ? 1 : exp(q·k/32)   (writes over A1/A2, which are dead now)
  gemm_bt<EP_EXP><<<dim3(S_ / 128, S_ / 128, B_), 256, 0, stream>>>(
      qb, kb, Pu, mask, S_, S_, DH, (long)S_ * DH, (long)S_ * DH);

  // column sums over q, then fold 1/colsum into vT
  hipMemsetAsync(ws + WS_CS, 0, (size_t)B_ * S_ * sizeof(float), stream);
  colsum_partial<<<dim3(S_ / 256, S_ / 256, B_), 256, 0, stream>>>(Pu, cs);
  scale_vt<<<(B_ * DH * S_ / 8) / 256, 256, 0, stream>>>(vTb, cs);

  // out[b,q,h] = sum_k Pu[b,q,k] * vT'[b,h,k]
  gemm_bt<EP_F32><<<dim3(DH / 128, S_ / 128, B_), 256, 0, stream>>>(
      Pu, vTb, (float*)d_out, nullptr, S_, DH, S_, (long)S_ * S_, (long)DH * S_);
}

// Round 2
// 240.571 us; speedup vs baseline: 1.1673x; 1.1673x over previous
//
#include <hip/hip_runtime.h>

typedef __bf16 bx8 __attribute__((ext_vector_type(8)));
typedef __bf16 bx4 __attribute__((ext_vector_type(4)));
typedef float  fx4 __attribute__((ext_vector_type(4)));

#define B_   4
#define S_   2048
#define DIN  1024
#define DH   1024

#define MB ((size_t)1 << 20)
// workspace layout (bytes)
#define WS_A1 ((size_t)0)          // seq1 bf16, 16MB   (aliased by Pu later)
#define WS_A2 ((size_t)16*MB)      // seq2 bf16, 16MB   (aliased by Pu later)
#define WS_PU ((size_t)0)          // exp-scores bf16, 32MB (after QKV done)
#define WS_WQ ((size_t)32*MB)
#define WS_WK ((size_t)34*MB)
#define WS_WV ((size_t)36*MB)
#define WS_Q  ((size_t)38*MB)      // q bf16 [B*S, DH] 16MB
#define WS_K  ((size_t)54*MB)      // k bf16 [B*S, DH] 16MB
#define WS_VT ((size_t)70*MB)      // v^T bf16 [B, DH, S] 16MB
#define WS_CS ((size_t)86*MB)      // colsum fp32 [B, S] 32KB

// ---------------------------------------------------------------- cvt f32->bf16
__global__ void cvt_f32_bf16(const float* __restrict__ in, __bf16* __restrict__ out) {
  size_t i = (size_t)blockIdx.x * blockDim.x + threadIdx.x;
  fx4 lo = ((const fx4*)in)[2 * i];
  fx4 hi = ((const fx4*)in)[2 * i + 1];
  bx8 o;
#pragma unroll
  for (int j = 0; j < 4; j++) { o[j] = (__bf16)lo[j]; o[j + 4] = (__bf16)hi[j]; }
  ((bx8*)out)[i] = o;
}

// ---------------------------------------------------------------- 8-phase GEMM C = A @ B^T
// BM=256, BN=128, BK=64, 512 threads = 8 waves (4 wr x 2 wc), per-wave 64x64.
// LDS (dynamic 96KB): 2 buffers x { A:[2kh][256][32] (2x16KB) + B:[2kh][128][32] (2x8KB) }.
// Quarters are contiguous => global_load_lds stays linear; bank swizzle is
// read-side XOR cb^=((row&6)<<3), inverse folded into per-lane GLOBAL src addr.
// Counted vmcnt ledger (per-wave instrs): stage order per tile t+1 =
// ph1:{A-k0 x2} ph2:{B-k0} ph3:{A-k1 x2} ph4:{B-k1}; vmcnt(3) at end of ph2/ph4
// retires exactly the 3 oldest (the quarters read next), leaving 3 in flight.

enum { EP_BF16 = 0, EP_VT = 1, EP_EXP = 2, EP_F32 = 3 };

#define GLD(gp, lp)                                                              \
  __builtin_amdgcn_global_load_lds(                                              \
      (const __attribute__((address_space(1))) void*)(const void*)(gp),          \
      (__attribute__((address_space(3))) void*)(void*)(lp), 16, 0, 0)

#define BARS()                                   \
  do {                                           \
    asm volatile("" ::: "memory");               \
    __builtin_amdgcn_s_barrier();                \
    __builtin_amdgcn_sched_barrier(0);           \
  } while (0)

#define VMC3_BARS()                                        \
  do {                                                     \
    asm volatile("s_waitcnt vmcnt(3)" ::: "memory");       \
    __builtin_amdgcn_s_barrier();                          \
    __builtin_amdgcn_sched_barrier(0);                     \
  } while (0)

#define MFMA1(m, n, av, bv) \
  acc[m][n] = __builtin_amdgcn_mfma_f32_16x16x32_bf16(av, bv, acc[m][n], 0, 0, 0)
#define MFMA8(mA, mB, a0_, a1_)                                              \
  MFMA1(mA, 0, a0_, b0); MFMA1(mA, 1, a0_, b1); MFMA1(mA, 2, a0_, b2);       \
  MFMA1(mA, 3, a0_, b3);                                                     \
  MFMA1(mB, 0, a1_, b0); MFMA1(mB, 1, a1_, b1); MFMA1(mB, 2, a1_, b2);       \
  MFMA1(mB, 3, a1_, b3)

template <int EPI>
__global__ __launch_bounds__(512, 2) void gemm8p(
    const __bf16* __restrict__ A, const __bf16* __restrict__ Bm,
    void* __restrict__ Cout, const int* __restrict__ Mask,
    int M, int N, int K, long sA, long sB) {
  extern __shared__ char smem[];
  const int bz = blockIdx.z;
  A  += (long)bz * sA;
  Bm += (long)bz * sB;
  const int brow = blockIdx.y * 256;
  const int bcol = blockIdx.x * 128;

  const int tid  = threadIdx.x;
  const int wid  = tid >> 6;
  const int lane = tid & 63;
  const int wr = wid >> 1;   // 0..3 -> wave rows wr*64
  const int wc = wid & 1;    // 0..1 -> wave cols wc*64

  fx4 acc[4][4] = {};

  // ---- staging addresses (per thread): 16B per lane, 64B logical rows
  const int sr  = tid >> 2;             // 0..127
  const int scb = (tid & 3) << 4;       // 0,16,32,48 (bytes)
  const int ssw = (scb ^ ((sr & 6) << 3)) >> 1;  // pre-swizzled col (elements)
  const __bf16* gA0 = A  + (size_t)(brow + sr) * K + ssw;         // A rows 0-127
  const __bf16* gA1 = A  + (size_t)(brow + sr + 128) * K + ssw;   // A rows 128-255
  const __bf16* gB  = Bm + (size_t)(bcol + sr) * K + ssw;         // B rows 0-127
  const int lw = wid << 10;  // wave slot in each 8KB stage unit

#define LA(buf, kh, i) (smem + (buf) * 49152 + (kh) * 16384 + (i) * 8192 + lw)
#define LB(buf, kh)    (smem + (buf) * 49152 + 32768 + (kh) * 8192 + lw)

  // ---- fragment read addresses (read-side swizzle; row&6 == (lane&15)&6)
  const int frow = lane & 15;
  const int fsw  = (((lane >> 4) << 4)) ^ ((frow & 6) << 3);   // swizzled col bytes
  const int arow = wr * 64 + frow;   // + m*16
  const int brw  = wc * 64 + frow;   // + n*16

#define LDSA(buf, kk, m) \
  (*(const bx8*)(smem + (buf) * 49152 + (kk) * 16384 + (arow + (m) * 16) * 64 + fsw))
#define LDSB(buf, kk, n) \
  (*(const bx8*)(smem + (buf) * 49152 + 32768 + (kk) * 8192 + (brw + (n) * 16) * 64 + fsw))

  // ---- prologue: stage tile 0 (order matters for the vmcnt ledger)
  GLD(gA0,      LA(0, 0, 0)); GLD(gA1,      LA(0, 0, 1)); GLD(gB,      LB(0, 0));
  GLD(gA0 + 32, LA(0, 1, 0)); GLD(gA1 + 32, LA(0, 1, 1)); GLD(gB + 32, LB(0, 1));
  VMC3_BARS();   // A-k0,B-k0 of tile0 resident; 3 in flight

  const int nt = K >> 6;
  for (int t = 0; t < nt; ++t) {
    const int cb = t & 1;
    const int nb = cb ^ 1;
    const int knext = (t + 1 < nt) ? (t + 1) * 64 : 0;  // wrap: junk loads, never read
    bx8 a0, a1, b0, b1, b2, b3;

    // ---- ph1: kk0, m0-1
    a0 = LDSA(cb, 0, 0); a1 = LDSA(cb, 0, 1);
    b0 = LDSB(cb, 0, 0); b1 = LDSB(cb, 0, 1); b2 = LDSB(cb, 0, 2); b3 = LDSB(cb, 0, 3);
    GLD(gA0 + knext, LA(nb, 0, 0)); GLD(gA1 + knext, LA(nb, 0, 1));
    BARS();
    __builtin_amdgcn_s_setprio(1); MFMA8(0, 1, a0, a1); __builtin_amdgcn_s_setprio(0);
    BARS();
    // ---- ph2: kk0, m2-3
    a0 = LDSA(cb, 0, 2); a1 = LDSA(cb, 0, 3);
    GLD(gB + knext, LB(nb, 0));
    BARS();
    __builtin_amdgcn_s_setprio(1); MFMA8(2, 3, a0, a1); __builtin_amdgcn_s_setprio(0);
    VMC3_BARS();   // retire A-k1,B-k1 of tile t (read by ph3/ph4)
    // ---- ph3: kk1, m0-1
    a0 = LDSA(cb, 1, 0); a1 = LDSA(cb, 1, 1);
    b0 = LDSB(cb, 1, 0); b1 = LDSB(cb, 1, 1); b2 = LDSB(cb, 1, 2); b3 = LDSB(cb, 1, 3);
    GLD(gA0 + knext + 32, LA(nb, 1, 0)); GLD(gA1 + knext + 32, LA(nb, 1, 1));
    BARS();
    __builtin_amdgcn_s_setprio(1); MFMA8(0, 1, a0, a1); __builtin_amdgcn_s_setprio(0);
    BARS();
    // ---- ph4: kk1, m2-3
    a0 = LDSA(cb, 1, 2); a1 = LDSA(cb, 1, 3);
    GLD(gB + knext + 32, LB(nb, 1));
    BARS();
    __builtin_amdgcn_s_setprio(1); MFMA8(2, 3, a0, a1); __builtin_amdgcn_s_setprio(0);
    VMC3_BARS();   // retire A-k0,B-k0 of tile t+1 (read by next ph1/ph2)
  }

  // ---- epilogue: C/D layout col = lane&15, row = (lane>>4)*4 + j  [verified m89]
  const int r0 = wr * 64 + (lane >> 4) * 4;
  const int c0 = wc * 64 + (lane & 15);

  if (EPI == EP_BF16) {
    __bf16* C = (__bf16*)Cout;
#pragma unroll
    for (int m = 0; m < 4; m++) {
      int row = brow + r0 + m * 16;
#pragma unroll
      for (int n = 0; n < 4; n++) {
        int col = bcol + c0 + n * 16;
#pragma unroll
        for (int j = 0; j < 4; j++)
          C[(size_t)(row + j) * N + col] = (__bf16)acc[m][n][j];
      }
    }
  } else if (EPI == EP_VT) {
    // write C^T into vT[b][col][s], b = row/2048, s = row%2048 (4 consecutive s)
    __bf16* C = (__bf16*)Cout;
#pragma unroll
    for (int m = 0; m < 4; m++) {
      int row  = brow + r0 + m * 16;
      size_t bb = (size_t)(row >> 11) << 21;  // batch * DH*S
      int sidx = row & 2047;
#pragma unroll
      for (int n = 0; n < 4; n++) {
        int col = bcol + c0 + n * 16;
        bx4 tv;
#pragma unroll
        for (int j = 0; j < 4; j++) tv[j] = (__bf16)acc[m][n][j];
        *(bx4*)&C[bb + (size_t)col * S_ + sidx] = tv;
      }
    }
  } else if (EPI == EP_EXP) {
    __bf16* C     = (__bf16*)Cout + (size_t)bz * ((size_t)S_ * S_);
    const int* Mk = Mask + (size_t)bz * ((size_t)S_ * S_);
#pragma unroll
    for (int m = 0; m < 4; m++) {
      int row = brow + r0 + m * 16;
#pragma unroll
      for (int n = 0; n < 4; n++) {
        int col = bcol + c0 + n * 16;
#pragma unroll
        for (int j = 0; j < 4; j++) {
          float s = acc[m][n][j] * 0.03125f;  // 1/sqrt(1024)
          float p = Mk[(size_t)(row + j) * N + col] ? 1.0f : __expf(s);
          C[(size_t)(row + j) * N + col] = (__bf16)p;
        }
      }
    }
  } else {  // EP_F32
    float* C = (float*)Cout + (size_t)bz * ((size_t)S_ * DH);
#pragma unroll
    for (int m = 0; m < 4; m++) {
      int row = brow + r0 + m * 16;
#pragma unroll
      for (int n = 0; n < 4; n++) {
        int col = bcol + c0 + n * 16;
#pragma unroll
        for (int j = 0; j < 4; j++)
          C[(size_t)(row + j) * N + col] = acc[m][n][j];
      }
    }
  }
}

// ---------------------------------------------------------------- column sums of Pu
__global__ void colsum_partial(const __bf16* __restrict__ Pu, float* __restrict__ cs) {
  int b  = blockIdx.z;
  int k  = blockIdx.x * 256 + threadIdx.x;
  int q0 = blockIdx.y * 256;
  const __bf16* P = Pu + (size_t)b * S_ * S_ + (size_t)q0 * S_ + k;
  float s = 0.f;
#pragma unroll 8
  for (int q = 0; q < 256; q++) s += (float)P[(size_t)q * S_];
  atomicAdd(&cs[b * S_ + k], s);
}

// ---------------------------------------------------------------- vT[b][h][k] /= colsum[b][k]
__global__ void scale_vt(__bf16* __restrict__ vT, const float* __restrict__ cs) {
  size_t i = (size_t)blockIdx.x * blockDim.x + threadIdx.x;
  size_t e = i * 8;
  int b = (int)(e >> 21);      // DH*S = 2^21 elems per batch
  int k = (int)(e & (S_ - 1)); // contiguous along k
  bx8 v = ((bx8*)vT)[i];
  const float* c = cs + (size_t)b * S_ + k;
#pragma unroll
  for (int j = 0; j < 8; j++) v[j] = (__bf16)((float)v[j] / c[j]);
  ((bx8*)vT)[i] = v;
}

// ---------------------------------------------------------------- launch
extern "C" void kernel_launch(void* const* d_in, const int* in_sizes, int n_in,
                              void* d_out, int out_size, void* d_ws, size_t ws_size,
                              hipStream_t stream) {
  const float* seq1 = (const float*)d_in[0];
  const float* seq2 = (const float*)d_in[1];
  const int*   mask = (const int*)d_in[2];
  const float* Wq   = (const float*)d_in[3];
  const float* Wk   = (const float*)d_in[4];
  const float* Wv   = (const float*)d_in[5];

  char* ws = (char*)d_ws;
  __bf16* A1  = (__bf16*)(ws + WS_A1);
  __bf16* A2  = (__bf16*)(ws + WS_A2);
  __bf16* Pu  = (__bf16*)(ws + WS_PU);
  __bf16* WQb = (__bf16*)(ws + WS_WQ);
  __bf16* WKb = (__bf16*)(ws + WS_WK);
  __bf16* WVb = (__bf16*)(ws + WS_WV);
  __bf16* qb  = (__bf16*)(ws + WS_Q);
  __bf16* kb  = (__bf16*)(ws + WS_K);
  __bf16* vTb = (__bf16*)(ws + WS_VT);
  float*  cs  = (float*)(ws + WS_CS);

  // allow 96KB dynamic LDS (host-side attribute set; not a stream op)
  static_assert(sizeof(void*) == 8, "");
  (void)hipFuncSetAttribute((const void*)gemm8p<EP_BF16>,
      hipFuncAttributeMaxDynamicSharedMemorySize, 98304);
  (void)hipFuncSetAttribute((const void*)gemm8p<EP_VT>,
      hipFuncAttributeMaxDynamicSharedMemorySize, 98304);
  (void)hipFuncSetAttribute((const void*)gemm8p<EP_EXP>,
      hipFuncAttributeMaxDynamicSharedMemorySize, 98304);
  (void)hipFuncSetAttribute((const void*)gemm8p<EP_F32>,
      hipFuncAttributeMaxDynamicSharedMemorySize, 98304);

  // fp32 -> bf16 conversions
  cvt_f32_bf16<<<4096, 256, 0, stream>>>(seq1, A1);
  cvt_f32_bf16<<<4096, 256, 0, stream>>>(seq2, A2);
  cvt_f32_bf16<<<512, 256, 0, stream>>>(Wq, WQb);
  cvt_f32_bf16<<<512, 256, 0, stream>>>(Wk, WKb);
  cvt_f32_bf16<<<512, 256, 0, stream>>>(Wv, WVb);

  // projections: q = seq1 @ Wq^T ; k = seq2 @ Wk^T ; vT = (seq2 @ Wv^T)^T
  gemm8p<EP_BF16><<<dim3(DH / 128, (B_ * S_) / 256, 1), 512, 98304, stream>>>(
      A1, WQb, qb, nullptr, B_ * S_, DH, DIN, 0, 0);
  gemm8p<EP_BF16><<<dim3(DH / 128, (B_ * S_) / 256, 1), 512, 98304, stream>>>(
      A2, WKb, kb, nullptr, B_ * S_, DH, DIN, 0, 0);
  gemm8p<EP_VT><<<dim3(DH / 128, (B_ * S_) / 256, 1), 512, 98304, stream>>>(
      A2, WVb, vTb, nullptr, B_ * S_, DH, DIN, 0, 0);

  // Pu[b,q,k] = mask ? 1 : exp(q·k/32)   (writes over A1/A2, which are dead now)
  gemm8p<EP_EXP><<<dim3(S_ / 128, S_ / 256, B_), 512, 98304, stream>>>(
      qb, kb, Pu, mask, S_, S_, DH, (long)S_ * DH, (long)S_ * DH);

  // column sums over q, then fold 1/colsum into vT
  hipMemsetAsync(ws + WS_CS, 0, (size_t)B_ * S_ * sizeof(float), stream);
  colsum_partial<<<dim3(S_ / 256, S_ / 256, B_), 256, 0, stream>>>(Pu, cs);
  scale_vt<<<(B_ * DH * S_ / 8) / 256, 256, 0, stream>>>(vTb, cs);

  // out[b,q,h] = sum_k Pu[b,q,k] * vT'[b,h,k]
  gemm8p<EP_F32><<<dim3(DH / 128, S_ / 256, B_), 512, 98304, stream>>>(
      Pu, vTb, (float*)d_out, nullptr, S_, DH, S_, (long)S_ * S_, (long)DH * S_);
}

// Round 3
// 227.153 us; speedup vs baseline: 1.2363x; 1.0591x over previous
//
#include <hip/hip_runtime.h>

typedef __bf16 bx8 __attribute__((ext_vector_type(8)));
typedef __bf16 bx4 __attribute__((ext_vector_type(4)));
typedef float  fx4 __attribute__((ext_vector_type(4)));

#define B_   4
#define S_   2048
#define DIN  1024
#define DH   1024

#define MB ((size_t)1 << 20)
// workspace layout (bytes)
#define WS_A1 ((size_t)0)          // seq1 bf16, 16MB   (aliased by Pu later)
#define WS_A2 ((size_t)16*MB)      // seq2 bf16, 16MB   (aliased by Pu later)
#define WS_PU ((size_t)0)          // exp-scores bf16, 32MB (after QKV done)
#define WS_WQ ((size_t)32*MB)
#define WS_WK ((size_t)34*MB)      // Wk and Wv contiguous => fused [Wk;Wv] N=2048
#define WS_WV ((size_t)36*MB)
#define WS_Q  ((size_t)38*MB)      // q bf16 [B*S, DH] 16MB
#define WS_K  ((size_t)54*MB)      // k bf16 [B*S, DH] 16MB
#define WS_VT ((size_t)70*MB)      // v^T bf16 [B, DH, S] 16MB
#define WS_CS ((size_t)86*MB)      // colsum fp32 [B, S] 32KB

// ---------------------------------------------------------------- cvt f32->bf16
__global__ void cvt_f32_bf16(const float* __restrict__ in, __bf16* __restrict__ out) {
  size_t i = (size_t)blockIdx.x * blockDim.x + threadIdx.x;
  fx4 lo = ((const fx4*)in)[2 * i];
  fx4 hi = ((const fx4*)in)[2 * i + 1];
  bx8 o;
#pragma unroll
  for (int j = 0; j < 4; j++) { o[j] = (__bf16)lo[j]; o[j + 4] = (__bf16)hi[j]; }
  ((bx8*)out)[i] = o;
}

// ---------------------------------------------------------------- 256x256 4-phase GEMM  C = A @ B^T
// BM=BN=256, BK=64, 512 thr = 8 waves (2 wr x 4 wc), per-wave 128x64, acc[8][4].
// LDS 128KB: buf*65536 + {A: [256][128B] at 0, B: [256][128B] at 32768}.
// Swizzle: lds colb = logical_colb ^ ((row&7)<<4); inverse folded into global src.
// Per K-tile: 4 phases x 16 MFMA; ds 12/4/4/4 (B frags read once, held in regs).
// Staging (2 GLD per thread per phase): ph0/ph1 -> A halves of t+1 (buf nb);
// ph2/ph3 -> B halves of t+2 (buf cb; its B region is dead after ph0).
// vmcnt(4) once per K-tile retires {B(t+1), A(t+1)}, keeps 4 loads in flight.

enum { EP_BF16 = 0, EP_KV = 1, EP_EXP = 2, EP_F32 = 3 };

#define GLD(gp, lp)                                                              \
  __builtin_amdgcn_global_load_lds(                                              \
      (const __attribute__((address_space(1))) void*)(const void*)(gp),          \
      (__attribute__((address_space(3))) void*)(void*)(lp), 16, 0, 0)

#define BARS()                                   \
  do {                                           \
    asm volatile("" ::: "memory");               \
    __builtin_amdgcn_s_barrier();                \
    __builtin_amdgcn_sched_barrier(0);           \
  } while (0)

#define VMC4_BARS()                                        \
  do {                                                     \
    asm volatile("s_waitcnt vmcnt(4)" ::: "memory");       \
    __builtin_amdgcn_s_barrier();                          \
    __builtin_amdgcn_sched_barrier(0);                     \
  } while (0)

#define MM(m, n, av, bv) \
  acc[m][n] = __builtin_amdgcn_mfma_f32_16x16x32_bf16(av, bv, acc[m][n], 0, 0, 0)
#define MFMA16(mA, mB) do {                                                       \
  MM(mA,0,a0k0,bk0n0); MM(mA,1,a0k0,bk0n1); MM(mA,2,a0k0,bk0n2); MM(mA,3,a0k0,bk0n3); \
  MM(mB,0,a1k0,bk0n0); MM(mB,1,a1k0,bk0n1); MM(mB,2,a1k0,bk0n2); MM(mB,3,a1k0,bk0n3); \
  MM(mA,0,a0k1,bk1n0); MM(mA,1,a0k1,bk1n1); MM(mA,2,a0k1,bk1n2); MM(mA,3,a0k1,bk1n3); \
  MM(mB,0,a1k1,bk1n0); MM(mB,1,a1k1,bk1n1); MM(mB,2,a1k1,bk1n2); MM(mB,3,a1k1,bk1n3); \
} while (0)

#define LDA_(buf, m, kk) (*(const bx8*)(aBase + (buf) * 65536 + (m) * 2048 + ((kk) ? c1s : c0s)))
#define LDB_(buf, n, kk) (*(const bx8*)(bBase + (buf) * 65536 + (n) * 2048 + ((kk) ? c1s : c0s)))
#define RD_A(cb, mA, mB)                             \
  a0k0 = LDA_(cb, mA, 0); a0k1 = LDA_(cb, mA, 1);    \
  a1k0 = LDA_(cb, mB, 0); a1k1 = LDA_(cb, mB, 1)

#define STAGE_A(kt, h, buf) do {                                                          \
  GLD(pA + (size_t)((h) * 128) * K + (kt),      smem + (buf) * 65536 + (h) * 16384 + tid * 16);        \
  GLD(pA + (size_t)((h) * 128 + 64) * K + (kt), smem + (buf) * 65536 + (h) * 16384 + 8192 + tid * 16); \
} while (0)
#define STAGE_B(kt, h, buf) do {                                                          \
  GLD(pB + (size_t)((h) * 128) * K + (kt),      smem + (buf) * 65536 + 32768 + (h) * 16384 + tid * 16);        \
  GLD(pB + (size_t)((h) * 128 + 64) * K + (kt), smem + (buf) * 65536 + 32768 + (h) * 16384 + 8192 + tid * 16); \
} while (0)

template <int EPI>
__global__ __launch_bounds__(512, 2) void gemm256(
    const __bf16* __restrict__ A, const __bf16* __restrict__ Bm,
    void* __restrict__ Cout, void* __restrict__ Cout2,
    const int* __restrict__ Mask, int N, int K, long sA, long sB) {
  extern __shared__ char smem[];
  const int bz = blockIdx.z;
  A  += (long)bz * sA;
  Bm += (long)bz * sB;
  const int brow = blockIdx.y * 256;
  const int bcol = blockIdx.x * 256;

  const int tid  = threadIdx.x;
  const int wid  = tid >> 6;
  const int lane = tid & 63;
  const int wr = wid >> 2;   // 0..1 -> rows wr*128
  const int wc = wid & 3;    // 0..3 -> cols wc*64

  fx4 acc[8][4] = {};

  // staging: thread covers lds flat tid*16 (+8192*i) per half; inverse swizzle on global col
  const int gcol = (((tid & 7) ^ ((tid >> 3) & 7)) << 3);  // elements
  const __bf16* pA = A  + (size_t)(brow + (tid >> 3)) * K + gcol;
  const __bf16* pB = Bm + (size_t)(bcol + (tid >> 3)) * K + gcol;

  // fragment read bases (read-side swizzle)
  const int frow = lane & 15;
  const int slot = (lane >> 4) << 4;
  const int c0s  = slot ^ ((frow & 7) << 4);
  const int c1s  = (64 + slot) ^ ((frow & 7) << 4);
  const char* aBase = smem + (wr * 128 + frow) * 128;
  const char* bBase = smem + 32768 + (wc * 64 + frow) * 128;

  // ---- prologue: tile0 fully + B halves of tile1; keep 4 loads in flight
  STAGE_A(0, 0, 0); STAGE_A(0, 1, 0);
  STAGE_B(0, 0, 0); STAGE_B(0, 1, 0);
  STAGE_B(64, 0, 1); STAGE_B(64, 1, 1);
  VMC4_BARS();

  const int nt = K >> 6;
  bx8 a0k0, a0k1, a1k0, a1k1;
  bx8 bk0n0, bk0n1, bk0n2, bk0n3, bk1n0, bk1n1, bk1n2, bk1n3;

  for (int t = 0; t < nt; ++t) {
    const int cb = t & 1, nb = cb ^ 1;
    const int kA = (t + 1 < nt) ? (t + 1) * 64 : 0;  // junk when past end, never read
    const int kB = (t + 2 < nt) ? (t + 2) * 64 : 0;

    // ---- ph0: m0,m1 (12 ds_reads: 4 A + 8 B)
    RD_A(cb, 0, 1);
    bk0n0 = LDB_(cb, 0, 0); bk0n1 = LDB_(cb, 1, 0); bk0n2 = LDB_(cb, 2, 0); bk0n3 = LDB_(cb, 3, 0);
    bk1n0 = LDB_(cb, 0, 1); bk1n1 = LDB_(cb, 1, 1); bk1n2 = LDB_(cb, 2, 1); bk1n3 = LDB_(cb, 3, 1);
    STAGE_A(kA, 0, nb);
    BARS();
    __builtin_amdgcn_s_setprio(1); MFMA16(0, 1); __builtin_amdgcn_s_setprio(0);
    BARS();
    // ---- ph1: m2,m3
    RD_A(cb, 2, 3);
    STAGE_A(kA, 1, nb);
    BARS();
    __builtin_amdgcn_s_setprio(1); MFMA16(2, 3); __builtin_amdgcn_s_setprio(0);
    BARS();
    // ---- ph2: m4,m5  (B region of buf cb is dead after ph0 -> stage t+2's B there)
    RD_A(cb, 4, 5);
    STAGE_B(kB, 0, cb);
    BARS();
    __builtin_amdgcn_s_setprio(1); MFMA16(4, 5); __builtin_amdgcn_s_setprio(0);
    BARS();
    // ---- ph3: m6,m7
    RD_A(cb, 6, 7);
    STAGE_B(kB, 1, cb);
    BARS();
    __builtin_amdgcn_s_setprio(1); MFMA16(6, 7); __builtin_amdgcn_s_setprio(0);
    VMC4_BARS();   // retires {B(t+1), A(t+1)}; keeps B(t+2) (4 loads) in flight
  }

  // ---- epilogue: C/D layout col = lane&15, row = (lane>>4)*4 + j  [verified m89]
  const int r0 = wr * 128 + (lane >> 4) * 4;
  const int c0 = wc * 64 + (lane & 15);

  if (EPI == EP_BF16) {
    __bf16* C = (__bf16*)Cout;
#pragma unroll
    for (int m = 0; m < 8; m++) {
      int row = brow + r0 + m * 16;
#pragma unroll
      for (int n = 0; n < 4; n++) {
        int col = bcol + c0 + n * 16;
#pragma unroll
        for (int j = 0; j < 4; j++)
          C[(size_t)(row + j) * N + col] = (__bf16)acc[m][n][j];
      }
    }
  } else if (EPI == EP_KV) {
    // cols 0-1023 -> k [8192,1024]; cols 1024-2047 -> vT[b][col-1024][s]
    __bf16* Ck = (__bf16*)Cout;
    __bf16* Cv = (__bf16*)Cout2;
    if (bcol < 1024) {
#pragma unroll
      for (int m = 0; m < 8; m++) {
        int row = brow + r0 + m * 16;
#pragma unroll
        for (int n = 0; n < 4; n++) {
          int col = bcol + c0 + n * 16;
#pragma unroll
          for (int j = 0; j < 4; j++)
            Ck[(size_t)(row + j) * 1024 + col] = (__bf16)acc[m][n][j];
        }
      }
    } else {
#pragma unroll
      for (int m = 0; m < 8; m++) {
        int row  = brow + r0 + m * 16;
        size_t bb = (size_t)(row >> 11) << 21;  // batch * DH*S
        int sidx = row & 2047;
#pragma unroll
        for (int n = 0; n < 4; n++) {
          int col = bcol + c0 + n * 16 - 1024;
          bx4 tv;
#pragma unroll
          for (int j = 0; j < 4; j++) tv[j] = (__bf16)acc[m][n][j];
          *(bx4*)&Cv[bb + (size_t)col * S_ + sidx] = tv;
        }
      }
    }
  } else if (EPI == EP_EXP) {
    __bf16* C     = (__bf16*)Cout + (size_t)bz * ((size_t)S_ * S_);
    const int* Mk = Mask + (size_t)bz * ((size_t)S_ * S_);
#pragma unroll
    for (int m = 0; m < 8; m++) {
      int row = brow + r0 + m * 16;
#pragma unroll
      for (int n = 0; n < 4; n++) {
        int col = bcol + c0 + n * 16;
#pragma unroll
        for (int j = 0; j < 4; j++) {
          float s = acc[m][n][j] * 0.03125f;  // 1/sqrt(1024)
          float p = Mk[(size_t)(row + j) * N + col] ? 1.0f : __expf(s);
          C[(size_t)(row + j) * N + col] = (__bf16)p;
        }
      }
    }
  } else {  // EP_F32
    float* C = (float*)Cout + (size_t)bz * ((size_t)S_ * DH);
#pragma unroll
    for (int m = 0; m < 8; m++) {
      int row = brow + r0 + m * 16;
#pragma unroll
      for (int n = 0; n < 4; n++) {
        int col = bcol + c0 + n * 16;
#pragma unroll
        for (int j = 0; j < 4; j++)
          C[(size_t)(row + j) * N + col] = acc[m][n][j];
      }
    }
  }
}

// ---------------------------------------------------------------- column sums of Pu
__global__ void colsum_partial(const __bf16* __restrict__ Pu, float* __restrict__ cs) {
  int b  = blockIdx.z;
  int k  = blockIdx.x * 256 + threadIdx.x;
  int q0 = blockIdx.y * 256;
  const __bf16* P = Pu + (size_t)b * S_ * S_ + (size_t)q0 * S_ + k;
  float s = 0.f;
#pragma unroll 8
  for (int q = 0; q < 256; q++) s += (float)P[(size_t)q * S_];
  atomicAdd(&cs[b * S_ + k], s);
}

// ---------------------------------------------------------------- vT[b][h][k] /= colsum[b][k]
__global__ void scale_vt(__bf16* __restrict__ vT, const float* __restrict__ cs) {
  size_t i = (size_t)blockIdx.x * blockDim.x + threadIdx.x;
  size_t e = i * 8;
  int b = (int)(e >> 21);      // DH*S = 2^21 elems per batch
  int k = (int)(e & (S_ - 1)); // contiguous along k
  bx8 v = ((bx8*)vT)[i];
  const float* c = cs + (size_t)b * S_ + k;
#pragma unroll
  for (int j = 0; j < 8; j++) v[j] = (__bf16)((float)v[j] / c[j]);
  ((bx8*)vT)[i] = v;
}

// ---------------------------------------------------------------- launch
extern "C" void kernel_launch(void* const* d_in, const int* in_sizes, int n_in,
                              void* d_out, int out_size, void* d_ws, size_t ws_size,
                              hipStream_t stream) {
  const float* seq1 = (const float*)d_in[0];
  const float* seq2 = (const float*)d_in[1];
  const int*   mask = (const int*)d_in[2];
  const float* Wq   = (const float*)d_in[3];
  const float* Wk   = (const float*)d_in[4];
  const float* Wv   = (const float*)d_in[5];

  char* ws = (char*)d_ws;
  __bf16* A1  = (__bf16*)(ws + WS_A1);
  __bf16* A2  = (__bf16*)(ws + WS_A2);
  __bf16* Pu  = (__bf16*)(ws + WS_PU);
  __bf16* WQb = (__bf16*)(ws + WS_WQ);
  __bf16* WKb = (__bf16*)(ws + WS_WK);   // [Wk;Wv] contiguous 2048x1024
  __bf16* WVb = (__bf16*)(ws + WS_WV);
  __bf16* qb  = (__bf16*)(ws + WS_Q);
  __bf16* kb  = (__bf16*)(ws + WS_K);
  __bf16* vTb = (__bf16*)(ws + WS_VT);
  float*  cs  = (float*)(ws + WS_CS);

  (void)hipFuncSetAttribute((const void*)gemm256<EP_BF16>,
      hipFuncAttributeMaxDynamicSharedMemorySize, 131072);
  (void)hipFuncSetAttribute((const void*)gemm256<EP_KV>,
      hipFuncAttributeMaxDynamicSharedMemorySize, 131072);
  (void)hipFuncSetAttribute((const void*)gemm256<EP_EXP>,
      hipFuncAttributeMaxDynamicSharedMemorySize, 131072);
  (void)hipFuncSetAttribute((const void*)gemm256<EP_F32>,
      hipFuncAttributeMaxDynamicSharedMemorySize, 131072);

  // fp32 -> bf16 conversions
  cvt_f32_bf16<<<4096, 256, 0, stream>>>(seq1, A1);
  cvt_f32_bf16<<<4096, 256, 0, stream>>>(seq2, A2);
  cvt_f32_bf16<<<512, 256, 0, stream>>>(Wq, WQb);
  cvt_f32_bf16<<<512, 256, 0, stream>>>(Wk, WKb);
  cvt_f32_bf16<<<512, 256, 0, stream>>>(Wv, WVb);

  // q = seq1 @ Wq^T   (M=8192, N=1024)
  gemm256<EP_BF16><<<dim3(DH / 256, (B_ * S_) / 256, 1), 512, 131072, stream>>>(
      A1, WQb, qb, nullptr, nullptr, DH, DIN, 0, 0);
  // [k | vT] = seq2 @ [Wk;Wv]^T  (M=8192, N=2048, split epilogue)
  gemm256<EP_KV><<<dim3(2048 / 256, (B_ * S_) / 256, 1), 512, 131072, stream>>>(
      A2, WKb, kb, vTb, nullptr, 2048, DIN, 0, 0);

  // Pu[b,q,k] = mask ? 1 : exp(q.k/32)   (overwrites A1/A2, dead now)
  gemm256<EP_EXP><<<dim3(S_ / 256, S_ / 256, B_), 512, 131072, stream>>>(
      qb, kb, Pu, nullptr, mask, S_, DH, (long)S_ * DH, (long)S_ * DH);

  // column sums over q, then fold 1/colsum into vT
  hipMemsetAsync(ws + WS_CS, 0, (size_t)B_ * S_ * sizeof(float), stream);
  colsum_partial<<<dim3(S_ / 256, S_ / 256, B_), 256, 0, stream>>>(Pu, cs);
  scale_vt<<<(B_ * DH * S_ / 8) / 256, 256, 0, stream>>>(vTb, cs);

  // out[b,q,h] = sum_k Pu[b,q,k] * vT'[b,h,k]   (M=2048, N=1024, K=2048)
  gemm256<EP_F32><<<dim3(DH / 256, S_ / 256, B_), 512, 131072, stream>>>(
      Pu, vTb, (float*)d_out, nullptr, nullptr, DH, S_, (long)S_ * S_, (long)DH * S_);
}